// Round 1
// baseline (2563.060 us; speedup 1.0000x reference)
//
#include <hip/hip_runtime.h>
#include <hip/hip_fp16.h>

#define AS1 __attribute__((address_space(1)))
#define AS3 __attribute__((address_space(3)))

typedef __bf16 bf16x8 __attribute__((ext_vector_type(8)));
typedef float f32x4 __attribute__((ext_vector_type(4)));

constexpr int NROWS = 16384;
constexpr int DIM   = 1024;
constexpr int KCENT = 12288;
constexpr int NCLS  = 4096;
constexpr int BM = 128, BN = 128, BK = 32;
constexpr int KSTEPS = DIM / BK;      // 32
constexpr int STATS_T = KCENT / 64;   // 192 stat tiles (64 cols each)

// ---------- kernel 0: fp32 -> (hi, lo) bf16 split (Ootomo decomposition) ----------
__global__ void split_convert(const float4* __restrict__ src,
                              ushort4* __restrict__ hi, ushort4* __restrict__ lo, int n4) {
  int i = blockIdx.x * blockDim.x + threadIdx.x;
  if (i >= n4) return;
  float4 v = src[i];
  float a[4] = {v.x, v.y, v.z, v.w};
  unsigned short hs[4], ls[4];
#pragma unroll
  for (int j = 0; j < 4; ++j) {
    unsigned u = __builtin_bit_cast(unsigned, a[j]);
    unsigned r = (u + 0x7fffu + ((u >> 16) & 1u)) & 0xffff0000u;  // RNE to bf16
    hs[j] = (unsigned short)(r >> 16);
    float hf = __builtin_bit_cast(float, r);
    float res = a[j] - hf;
    unsigned u2 = __builtin_bit_cast(unsigned, res);
    unsigned r2 = (u2 + 0x7fffu + ((u2 >> 16) & 1u)) >> 16;
    ls[j] = (unsigned short)r2;
  }
  hi[i] = make_ushort4(hs[0], hs[1], hs[2], hs[3]);
  lo[i] = make_ushort4(ls[0], ls[1], ls[2], ls[3]);
}

// ---------- kernel 1: split-bf16 GEMM + per-tile softmax stats epilogue ----------
// sim[r][c] = X[r]·C[c]; stores exp(sim - m_tile) as fp16, (m_tile, sumexp_tile) per (row, 64-col tile)
__launch_bounds__(256, 2)
__global__ void gemm_softmax(const __bf16* __restrict__ Xh, const __bf16* __restrict__ Xl,
                             const __bf16* __restrict__ Ch, const __bf16* __restrict__ Cl,
                             _Float16* __restrict__ expo, float2* __restrict__ stats,
                             int row0) {
  __shared__ __bf16 sAh[BM * BK], sAl[BM * BK], sBh[BM * BK], sBl[BM * BK];
  const int tid  = threadIdx.x;
  const int lane = tid & 63;
  const int wv   = tid >> 6;
  const int wr   = wv >> 1, wc = wv & 1;   // 2x2 wave grid, each wave owns 64x64
  const int bm = blockIdx.x, bn = blockIdx.y;
  const size_t arow0 = (size_t)row0 + (size_t)bm * BM;  // global X row base
  const size_t brow0 = (size_t)bn * BN;                 // centroid row base
  const int lbase = bm * BM;                            // chunk-local row base

  f32x4 acc[4][4] = {};

  // staging: issue iss in [0,8) covers LDS bytes iss*1024..+1024 of a [128][32] bf16 tile
  const int srow = lane >> 2;            // + iss*16
  const int scol = (lane & 3) * 8;       // elements within row

  for (int ks = 0; ks < KSTEPS; ++ks) {
    __syncthreads();  // previous iteration's ds_reads done before overwrite
    const int kcol = ks * BK;
#pragma unroll
    for (int s = 0; s < 2; ++s) {
      const int iss = wv * 2 + s;
      const int r = iss * 16 + srow;
      const size_t ga = (arow0 + (size_t)r) * DIM + kcol + scol;
      const size_t gb = (brow0 + (size_t)r) * DIM + kcol + scol;
      const int lo_off = iss * 512;  // elements
      __builtin_amdgcn_global_load_lds((const AS1 void*)(Xh + ga), (AS3 void*)(sAh + lo_off), 16, 0, 0);
      __builtin_amdgcn_global_load_lds((const AS1 void*)(Xl + ga), (AS3 void*)(sAl + lo_off), 16, 0, 0);
      __builtin_amdgcn_global_load_lds((const AS1 void*)(Ch + gb), (AS3 void*)(sBh + lo_off), 16, 0, 0);
      __builtin_amdgcn_global_load_lds((const AS1 void*)(Cl + gb), (AS3 void*)(sBl + lo_off), 16, 0, 0);
    }
    __syncthreads();  // staging complete

    bf16x8 ah[4], al[4], bh[4], bl[4];
    const int kk = (lane >> 4) * 8;
    const int rsel = lane & 15;
#pragma unroll
    for (int m = 0; m < 4; ++m) {
      const int ar = wr * 64 + m * 16 + rsel;
      ah[m] = *(const bf16x8*)(sAh + ar * BK + kk);
      al[m] = *(const bf16x8*)(sAl + ar * BK + kk);
      const int br = wc * 64 + m * 16 + rsel;
      bh[m] = *(const bf16x8*)(sBh + br * BK + kk);
      bl[m] = *(const bf16x8*)(sBl + br * BK + kk);
    }
#pragma unroll
    for (int m = 0; m < 4; ++m)
#pragma unroll
      for (int n = 0; n < 4; ++n) {
        acc[m][n] = __builtin_amdgcn_mfma_f32_16x16x32_bf16(ah[m], bh[n], acc[m][n], 0, 0, 0);
        acc[m][n] = __builtin_amdgcn_mfma_f32_16x16x32_bf16(ah[m], bl[n], acc[m][n], 0, 0, 0);
        acc[m][n] = __builtin_amdgcn_mfma_f32_16x16x32_bf16(al[m], bh[n], acc[m][n], 0, 0, 0);
      }
  }

  // epilogue: C/D layout col = lane&15, row = (lane>>4)*4 + reg  [m89-verified]
  const int g  = lane >> 4;
  const int cl = lane & 15;
  const int tileIdx = bn * 2 + wc;
#pragma unroll
  for (int m = 0; m < 4; ++m) {
#pragma unroll
    for (int j = 0; j < 4; ++j) {
      const int lrow = lbase + wr * 64 + m * 16 + g * 4 + j;  // chunk-local row
      float v0 = acc[m][0][j], v1 = acc[m][1][j], v2 = acc[m][2][j], v3 = acc[m][3][j];
      float mx = fmaxf(fmaxf(v0, v1), fmaxf(v2, v3));
#pragma unroll
      for (int s2 = 1; s2 < 16; s2 <<= 1) mx = fmaxf(mx, __shfl_xor(mx, s2, 64));
      float p0 = __expf(v0 - mx), p1 = __expf(v1 - mx), p2 = __expf(v2 - mx), p3 = __expf(v3 - mx);
      float sm = p0 + p1 + p2 + p3;
#pragma unroll
      for (int s2 = 1; s2 < 16; s2 <<= 1) sm += __shfl_xor(sm, s2, 64);
      _Float16* ep = expo + (size_t)lrow * KCENT + brow0 + wc * 64;
      ep[ 0 + cl] = (_Float16)p0;
      ep[16 + cl] = (_Float16)p1;
      ep[32 + cl] = (_Float16)p2;
      ep[48 + cl] = (_Float16)p3;
      if (cl == 0) stats[(size_t)lrow * STATS_T + tileIdx] = make_float2(mx, sm);
    }
  }
}

// ---------- kernel 2: combine per-tile stats -> per-tile coefficients exp(m_t-m)/Z ----------
__global__ void combine_stats(const float2* __restrict__ stats, float* __restrict__ coeff) {
  const int lane = threadIdx.x & 63;
  const int row  = blockIdx.x * 4 + (threadIdx.x >> 6);
  const float2* st = stats + (size_t)row * STATS_T;
  float mt[3], zt[3];
  float m = -3.4e38f;
#pragma unroll
  for (int i = 0; i < 3; ++i) {
    float2 s = st[lane + i * 64];
    mt[i] = s.x; zt[i] = s.y;
    m = fmaxf(m, s.x);
  }
#pragma unroll
  for (int s2 = 1; s2 < 64; s2 <<= 1) m = fmaxf(m, __shfl_xor(m, s2, 64));
  float z = 0.f;
#pragma unroll
  for (int i = 0; i < 3; ++i) z += zt[i] * __expf(mt[i] - m);
#pragma unroll
  for (int s2 = 1; s2 < 64; s2 <<= 1) z += __shfl_xor(z, s2, 64);
  const float inv = 1.0f / z;
  float* cf = coeff + (size_t)row * STATS_T;
#pragma unroll
  for (int i = 0; i < 3; ++i) cf[lane + i * 64] = __expf(mt[i] - m) * inv;
}

// ---------- kernel 3: scatter exp/Z into 4096 class bins (one row per block) ----------
__launch_bounds__(256)
__global__ void scatter_classes(const _Float16* __restrict__ expo, const float* __restrict__ coeff,
                                const int* __restrict__ labels, float* __restrict__ out, int row0) {
  __shared__ __align__(16) float bins[NCLS];
  __shared__ float cf[STATS_T];
  const int row = blockIdx.x;
  const int tid = threadIdx.x;
  for (int i = tid; i < NCLS; i += 256) bins[i] = 0.f;
  if (tid < STATS_T) cf[tid] = coeff[(size_t)row * STATS_T + tid];
  __syncthreads();
  const _Float16* ep = expo + (size_t)row * KCENT;
  for (int k = tid; k < KCENT; k += 256) {
    float p = (float)ep[k] * cf[k >> 6];
    atomicAdd(&bins[labels[k]], p);
  }
  __syncthreads();
  float4* orow = (float4*)(out + (size_t)(row0 + row) * NCLS);
  const float4* b4 = (const float4*)bins;
  for (int i = tid; i < NCLS / 4; i += 256) orow[i] = b4[i];
}

extern "C" void kernel_launch(void* const* d_in, const int* in_sizes, int n_in,
                              void* d_out, int out_size, void* d_ws, size_t ws_size,
                              hipStream_t stream) {
  (void)in_sizes; (void)n_in; (void)out_size;
  const float* X = (const float*)d_in[0];
  const float* C = (const float*)d_in[1];
  const int* labels = (const int*)d_in[2];
  float* out = (float*)d_out;

  char* ws = (char*)d_ws;
  size_t off = 0;
  auto carve = [&](size_t bytes) -> char* {
    char* p = ws + off;
    off += (bytes + 255) & ~(size_t)255;
    return p;
  };
  __bf16* Xh = (__bf16*)carve((size_t)NROWS * DIM * 2);
  __bf16* Xl = (__bf16*)carve((size_t)NROWS * DIM * 2);
  __bf16* Ch = (__bf16*)carve((size_t)KCENT * DIM * 2);
  __bf16* Cl = (__bf16*)carve((size_t)KCENT * DIM * 2);
  const size_t fixed = off;

  // chunk rows so per-chunk scratch (fp16 exp + stats + coeff) fits ws
  const size_t per_row = (size_t)KCENT * 2 + (size_t)STATS_T * 8 + (size_t)STATS_T * 4;
  size_t avail = (ws_size > fixed + 4096) ? (ws_size - fixed - 4096) : 0;
  long Rmax = (long)(avail / per_row);
  Rmax = (Rmax / 128) * 128;
  if (Rmax < 128) Rmax = 128;
  if (Rmax > NROWS) Rmax = NROWS;
  _Float16* expo = (_Float16*)carve((size_t)Rmax * KCENT * 2);
  float2* stats  = (float2*)carve((size_t)Rmax * STATS_T * 8);
  float* coeff   = (float*)carve((size_t)Rmax * STATS_T * 4);

  {
    int n4x = NROWS * DIM / 4;
    split_convert<<<(n4x + 255) / 256, 256, 0, stream>>>((const float4*)X, (ushort4*)Xh, (ushort4*)Xl, n4x);
    int n4c = KCENT * DIM / 4;
    split_convert<<<(n4c + 255) / 256, 256, 0, stream>>>((const float4*)C, (ushort4*)Ch, (ushort4*)Cl, n4c);
  }

  for (int r0 = 0; r0 < NROWS; r0 += (int)Rmax) {
    int R = (NROWS - r0 < (int)Rmax) ? (NROWS - r0) : (int)Rmax;
    dim3 grid(R / BM, KCENT / BN);
    gemm_softmax<<<grid, 256, 0, stream>>>(Xh, Xl, Ch, Cl, expo, stats, r0);
    combine_stats<<<R / 4, 256, 0, stream>>>(stats, coeff);
    scatter_classes<<<R, 256, 0, stream>>>(expo, coeff, labels, out, r0);
  }
}